// Round 1
// baseline (931.325 us; speedup 1.0000x reference)
//
#include <hip/hip_runtime.h>
#include <cstdint>
#include <cstddef>

#define E 1024
#define NB 32768
#define BM 128
#define BN 128

typedef __attribute__((ext_vector_type(4))) float f32x4;
typedef __attribute__((ext_vector_type(8))) short bf16x8;

__device__ __forceinline__ short f2bfs(float x) {
    __bf16 h = (__bf16)x;
    return __builtin_bit_cast(short, h);
}
__device__ __forceinline__ float bf2f(unsigned short u) {
    union { unsigned u; float f; } v;
    v.u = ((unsigned)u) << 16;
    return v.f;
}
__device__ __forceinline__ bf16x8 cvt8(f32x4 lo, f32x4 hi) {
    bf16x8 r;
#pragma unroll
    for (int j = 0; j < 4; ++j) { r[j] = f2bfs(lo[j]); r[j + 4] = f2bfs(hi[j]); }
    return r;
}

// ---------------- transpose f32 -> bf16 (Wv -> WvT) ----------------
__global__ __launch_bounds__(256) void wv_transpose(const float* W0, short* T0,
                                                    const float* W1, short* T1) {
    const float* W = blockIdx.z ? W1 : W0;
    short* T = blockIdx.z ? T1 : T0;
    __shared__ float tile[32][33];
    const int j0 = blockIdx.x * 32, i0 = blockIdx.y * 32;
    const int tx = threadIdx.x, ty = threadIdx.y; // (32,8)
#pragma unroll
    for (int r = 0; r < 4; ++r)
        tile[ty + 8 * r][tx] = W[(size_t)(i0 + ty + 8 * r) * E + j0 + tx];
    __syncthreads();
#pragma unroll
    for (int r = 0; r < 4; ++r)
        T[(size_t)(j0 + ty + 8 * r) * E + i0 + tx] = f2bfs(tile[tx][ty + 8 * r]);
}

// ---------------- c[n] = sum_i O[n][i]*bv[i] + ob[n] ----------------
__global__ __launch_bounds__(256) void bias_fuse(const float* O0, const float* bv0, const float* ob0, float* c0,
                                                 const float* O1, const float* bv1, const float* ob1, float* c1) {
    const float* O  = blockIdx.z ? O1 : O0;
    const float* bv = blockIdx.z ? bv1 : bv0;
    const float* ob = blockIdx.z ? ob1 : ob0;
    float* c = blockIdx.z ? c1 : c0;
    const int n = blockIdx.x, t = threadIdx.x;
    float s = 0.f;
    for (int i = t; i < E; i += 256) s += O[(size_t)n * E + i] * bv[i];
#pragma unroll
    for (int o = 32; o; o >>= 1) s += __shfl_down(s, o);
    __shared__ float rs[4];
    if ((t & 63) == 0) rs[t >> 6] = s;
    __syncthreads();
    if (t == 0) c[n] = rs[0] + rs[1] + rs[2] + rs[3] + ob[n];
}

// ---------------- GEMM: C[m][n] = sum_k A[m][k]*B[n][k] + bias[n] ----------------
struct GemmArgs {
    const float* A;   // M x 1024 f32
    const short* B;   // 1024 x 1024 bf16 (B^T layout: [n][k])
    const float* bias; // 1024 f32 or nullptr
    void* C;          // M x 1024, CT
};

struct Frags { bf16x8 a[2][4]; bf16x8 b[2][4]; };

__device__ __forceinline__ void load_frags(Frags& f, const float* Abase, const short* Bbase, int kt) {
#pragma unroll
    for (int m = 0; m < 4; ++m) {
        const float* ap = Abase + (size_t)m * 16 * E + kt;
        f32x4 x0 = *(const f32x4*)(ap);
        f32x4 x1 = *(const f32x4*)(ap + 4);
        f32x4 x2 = *(const f32x4*)(ap + 32);
        f32x4 x3 = *(const f32x4*)(ap + 36);
        f.a[0][m] = cvt8(x0, x1);
        f.a[1][m] = cvt8(x2, x3);
    }
#pragma unroll
    for (int n = 0; n < 4; ++n) {
        const short* bp = Bbase + (size_t)n * 16 * E + kt;
        f.b[0][n] = *(const bf16x8*)(bp);
        f.b[1][n] = *(const bf16x8*)(bp + 32);
    }
}

__device__ __forceinline__ void mfma_step(f32x4 (&acc)[4][4], const Frags& f) {
#pragma unroll
    for (int kk = 0; kk < 2; ++kk)
#pragma unroll
        for (int m = 0; m < 4; ++m)
#pragma unroll
            for (int n = 0; n < 4; ++n)
                acc[m][n] = __builtin_amdgcn_mfma_f32_16x16x32_bf16(f.a[kk][m], f.b[kk][n], acc[m][n], 0, 0, 0);
}

__device__ __forceinline__ void cstore(float* p, float v) { *p = v; }
__device__ __forceinline__ void cstore(short* p, float v) { *p = f2bfs(v); }

template <typename CT>
__global__ __launch_bounds__(256, 2) void gemm_bt(GemmArgs g0, GemmArgs g1) {
    GemmArgs ga = (blockIdx.z == 0) ? g0 : g1;
    const int lane = threadIdx.x & 63;
    const int wid = threadIdx.x >> 6;
    const int wm = wid >> 1, wn = wid & 1;
    const int r16 = lane & 15;
    const int kg = lane >> 4;

    const size_t arow = (size_t)blockIdx.x * BM + wm * 64 + r16;
    const size_t brow = (size_t)blockIdx.y * BN + wn * 64 + r16;
    const float* Abase = ga.A + arow * E + kg * 8;
    const short* Bbase = ga.B + brow * E + kg * 8;

    f32x4 acc[4][4] = {};

    Frags cur, nxt;
    load_frags(cur, Abase, Bbase, 0);
#pragma unroll 1
    for (int kt = 0; kt < E; kt += 128) {
        load_frags(nxt, Abase, Bbase, kt + 64);
        mfma_step(acc, cur);
        load_frags(cur, Abase, Bbase, (kt + 128) & (E - 1));
        mfma_step(acc, nxt);
    }

    // epilogue: C/D layout (16x16): col = lane&15, row = (lane>>4)*4 + q  [m89]
    const int ccol0 = blockIdx.y * BN + wn * 64 + r16;
    const int crow0 = blockIdx.x * BM + wm * 64 + kg * 4;
    float bn_[4];
#pragma unroll
    for (int n = 0; n < 4; ++n) bn_[n] = ga.bias ? ga.bias[ccol0 + n * 16] : 0.f;
    CT* Cp = (CT*)ga.C;
#pragma unroll
    for (int m = 0; m < 4; ++m)
#pragma unroll
        for (int n = 0; n < 4; ++n)
#pragma unroll
            for (int q = 0; q < 4; ++q) {
                size_t idx = (size_t)(crow0 + m * 16 + q) * E + ccol0 + n * 16;
                cstore(Cp + idx, acc[m][n][q] + bn_[n]);
            }
}

// ---------------- fused residual + LayerNorm (in-place on att/out) ----------------
struct LnArgs {
    const float* emb;  // B x E
    const float* att;  // B x E (aliases out)
    const float* scale; // 1
    const float* g;    // E
    const float* b;    // E
    float* out;        // B x E
};

__global__ __launch_bounds__(256) void ln_fused(LnArgs l0, LnArgs l1) {
    LnArgs la = blockIdx.z ? l1 : l0;
    const int row = blockIdx.x;
    const int t = threadIdx.x;
    const size_t off = (size_t)row * E + t * 4;
    f32x4 e = *(const f32x4*)(la.emb + off);
    f32x4 a = *(const f32x4*)(la.att + off);
    const float s = la.scale[0];
    f32x4 x = e + a * s;
    float sum = x[0] + x[1] + x[2] + x[3];
    float sq = x[0] * x[0] + x[1] * x[1] + x[2] * x[2] + x[3] * x[3];
#pragma unroll
    for (int o = 32; o; o >>= 1) { sum += __shfl_down(sum, o); sq += __shfl_down(sq, o); }
    __shared__ float rs[8];
    const int lane = t & 63, wid = t >> 6;
    if (lane == 0) { rs[wid] = sum; rs[wid + 4] = sq; }
    __syncthreads();
    sum = rs[0] + rs[1] + rs[2] + rs[3];
    sq = rs[4] + rs[5] + rs[6] + rs[7];
    const float mean = sum * (1.0f / E);
    const float var = sq * (1.0f / E) - mean * mean;
    const float rstd = rsqrtf(var + 1e-5f);
    f32x4 gv = *(const f32x4*)(la.g + t * 4);
    f32x4 bv = *(const f32x4*)(la.b + t * 4);
    f32x4 o = (x - mean) * rstd * gv + bv;
    *(f32x4*)(la.out + off) = o;
}

extern "C" void kernel_launch(void* const* d_in, const int* in_sizes, int n_in,
                              void* d_out, int out_size, void* d_ws, size_t ws_size,
                              hipStream_t stream) {
    const float* user_emb = (const float*)d_in[0];
    const float* item_emb = (const float*)d_in[1];
    const float* u2i_in_w = (const float*)d_in[2];
    const float* u2i_in_b = (const float*)d_in[3];
    const float* u2i_out_w = (const float*)d_in[4];
    const float* u2i_out_b = (const float*)d_in[5];
    const float* i2u_in_w = (const float*)d_in[6];
    const float* i2u_in_b = (const float*)d_in[7];
    const float* i2u_out_w = (const float*)d_in[8];
    const float* i2u_out_b = (const float*)d_in[9];
    const float* user_g = (const float*)d_in[10];
    const float* user_b = (const float*)d_in[11];
    const float* item_g = (const float*)d_in[12];
    const float* item_b = (const float*)d_in[13];
    const float* alpha = (const float*)d_in[14];
    const float* beta = (const float*)d_in[15];

    float* out = (float*)d_out;
    float* out_u = out;               // user_evolved, also att_u scratch (f32)
    float* out_i = out + (size_t)NB * E; // item_evolved, also att_i scratch

    // workspace layout (~8 MB)
    short* WvT1 = (short*)d_ws;
    short* WvT2 = WvT1 + (size_t)E * E;
    short* M1 = WvT2 + (size_t)E * E;
    short* M2 = M1 + (size_t)E * E;
    float* c1 = (float*)(M2 + (size_t)E * E);
    float* c2 = c1 + E;

    const dim3 b256(256);

    // 1) WvT = transpose(in_w[2E:3E]) in bf16
    wv_transpose<<<dim3(32, 32, 2), dim3(32, 8), 0, stream>>>(
        u2i_in_w + 2 * (size_t)E * E, WvT1, i2u_in_w + 2 * (size_t)E * E, WvT2);

    // 2) c = O @ bv + ob
    bias_fuse<<<dim3(E, 1, 2), b256, 0, stream>>>(
        u2i_out_w, u2i_in_b + 2 * E, u2i_out_b, c1,
        i2u_out_w, i2u_in_b + 2 * E, i2u_out_b, c2);

    // 3) M = O @ Wv   (bf16 output, [n][k] layout)
    gemm_bt<short><<<dim3(E / BM, E / BN, 2), b256, 0, stream>>>(
        GemmArgs{u2i_out_w, WvT1, nullptr, (void*)M1},
        GemmArgs{i2u_out_w, WvT2, nullptr, (void*)M2});

    // 4) att = kv_emb @ M^T + c   (f32, straight into d_out halves)
    gemm_bt<float><<<dim3(NB / BM, E / BN, 2), b256, 0, stream>>>(
        GemmArgs{item_emb, M1, c1, (void*)out_u},
        GemmArgs{user_emb, M2, c2, (void*)out_i});

    // 5) out = LayerNorm(emb + scale*att) * g + b   (in-place on att)
    ln_fused<<<dim3(NB, 1, 2), b256, 0, stream>>>(
        LnArgs{user_emb, out_u, alpha, user_g, user_b, out_u},
        LnArgs{item_emb, out_i, beta, item_g, item_b, out_i});
}

// Round 2
// 441.428 us; speedup vs baseline: 2.1098x; 2.1098x over previous
//
#include <hip/hip_runtime.h>
#include <cstdint>
#include <cstddef>

#define E 1024
#define NB 32768
#define BM 128
#define BN 128

typedef __attribute__((ext_vector_type(4))) float f32x4;
typedef __attribute__((ext_vector_type(8))) short bf16x8;

__device__ __forceinline__ short f2bfs(float x) {
    __bf16 h = (__bf16)x;
    return __builtin_bit_cast(short, h);
}
__device__ __forceinline__ bf16x8 cvt8(f32x4 lo, f32x4 hi) {
    bf16x8 r;
#pragma unroll
    for (int j = 0; j < 4; ++j) { r[j] = f2bfs(lo[j]); r[j + 4] = f2bfs(hi[j]); }
    return r;
}

__device__ __forceinline__ void gload16(const void* g, void* l) {
    __builtin_amdgcn_global_load_lds(
        (__attribute__((address_space(1))) void*)g,
        (__attribute__((address_space(3))) void*)l, 16, 0, 0);
}

// ---------------- transpose f32 -> bf16 (Wv -> WvT) ----------------
__global__ __launch_bounds__(256) void wv_transpose(const float* W0, short* T0,
                                                    const float* W1, short* T1) {
    const float* W = blockIdx.z ? W1 : W0;
    short* T = blockIdx.z ? T1 : T0;
    __shared__ float tile[32][33];
    const int j0 = blockIdx.x * 32, i0 = blockIdx.y * 32;
    const int tx = threadIdx.x, ty = threadIdx.y; // (32,8)
#pragma unroll
    for (int r = 0; r < 4; ++r)
        tile[ty + 8 * r][tx] = W[(size_t)(i0 + ty + 8 * r) * E + j0 + tx];
    __syncthreads();
#pragma unroll
    for (int r = 0; r < 4; ++r)
        T[(size_t)(j0 + ty + 8 * r) * E + i0 + tx] = f2bfs(tile[tx][ty + 8 * r]);
}

// ---------------- c[n] = sum_i O[n][i]*bv[i] + ob[n] ----------------
__global__ __launch_bounds__(256) void bias_fuse(const float* O0, const float* bv0, const float* ob0, float* c0,
                                                 const float* O1, const float* bv1, const float* ob1, float* c1) {
    const float* O  = blockIdx.z ? O1 : O0;
    const float* bv = blockIdx.z ? bv1 : bv0;
    const float* ob = blockIdx.z ? ob1 : ob0;
    float* c = blockIdx.z ? c1 : c0;
    const int n = blockIdx.x, t = threadIdx.x;
    float s = 0.f;
    for (int i = t; i < E; i += 256) s += O[(size_t)n * E + i] * bv[i];
#pragma unroll
    for (int o = 32; o; o >>= 1) s += __shfl_down(s, o);
    __shared__ float rs[4];
    if ((t & 63) == 0) rs[t >> 6] = s;
    __syncthreads();
    if (t == 0) c[n] = rs[0] + rs[1] + rs[2] + rs[3] + ob[n];
}

// ---------------- GEMM: C[m][n] = sum_k A[m][k]*B[n][k] + bias[n] ----------------
// A: f32 [M][1024]; B: bf16 [1024][1024] ([n][k]); LDS-staged, double-buffered,
// XOR-swizzled (rule #21: linear gload_lds dest + inverse-swizzled source + swizzled read).
struct GemmArgs {
    const float* A;
    const short* B;
    const float* bias;
    void* C;
};

__device__ __forceinline__ void cstore(float* p, float v) { *p = v; }
__device__ __forceinline__ void cstore(short* p, float v) { *p = f2bfs(v); }

template <typename CT>
__global__ __launch_bounds__(256, 3) void gemm_bt(GemmArgs g0, GemmArgs g1, int mb) {
    // bijective XCD swizzle (nwg divisible by 8), n-block fastest within chunk
    const int nwg = gridDim.x;
    const int q = nwg >> 3;
    const int wgid = (blockIdx.x & 7) * q + (blockIdx.x >> 3);
    const int per = mb * 8;
    const int z = wgid / per;
    const int rem = wgid - z * per;
    const int bx = rem >> 3;   // m block
    const int by = rem & 7;    // n block
    GemmArgs ga = z ? g1 : g0;

    // per buffer: A f32 [128 rows][128B] at 0 (16KB), B bf16 [128 rows][64B] at 16KB (8KB)
    __shared__ __align__(16) char lds[2][24576];

    const int t = threadIdx.x;
    const int l = t & 63, w = t >> 6;
    const int am0 = bx * BM, bn0 = by * BN;

    // --- staging: per-thread global source pointers (inverse-swizzled) ---
    const float* gA[4];
#pragma unroll
    for (int i = 0; i < 4; ++i) {
        int c = i * 4 + w;               // 1KB chunk id, 16 chunks for A
        int row = c * 8 + (l >> 3);      // L/128
        int slot = (l & 7) ^ (row & 7);  // involution
        gA[i] = ga.A + (size_t)(am0 + row) * E + slot * 4;
    }
    const short* gB[2];
#pragma unroll
    for (int i = 0; i < 2; ++i) {
        int c = i * 4 + w;               // 8 chunks for B
        int row = c * 16 + (l >> 2);     // L/64
        int slot = (l & 3) ^ ((row >> 1) & 3);
        gB[i] = ga.B + (size_t)(bn0 + row) * E + slot * 8;
    }

    auto stage = [&](int buf, int kt) {
#pragma unroll
        for (int i = 0; i < 4; ++i)
            gload16(gA[i] + kt, &lds[buf][(i * 4 + w) * 1024]);
#pragma unroll
        for (int i = 0; i < 2; ++i)
            gload16(gB[i] + kt, &lds[buf][16384 + (i * 4 + w) * 1024]);
    };

    // --- read-side LDS byte offsets (swizzled) ---
    const int wm = w >> 1, wn = w & 1;
    const int r16 = l & 15, kg = l >> 4;
    int aoff[4][2], boff[4];
#pragma unroll
    for (int m = 0; m < 4; ++m) {
        int row = wm * 64 + m * 16 + r16;
        aoff[m][0] = row * 128 + ((kg * 2) ^ (row & 7)) * 16;
        aoff[m][1] = row * 128 + ((kg * 2 + 1) ^ (row & 7)) * 16;
    }
#pragma unroll
    for (int n = 0; n < 4; ++n) {
        int row = wn * 64 + n * 16 + r16;
        boff[n] = 16384 + row * 64 + (kg ^ ((row >> 1) & 3)) * 16;
    }

    f32x4 acc[4][4] = {};

    auto compute = [&](int buf) {
        bf16x8 a[4], b[4];
#pragma unroll
        for (int m = 0; m < 4; ++m) {
            f32x4 lo = *(const f32x4*)&lds[buf][aoff[m][0]];
            f32x4 hi = *(const f32x4*)&lds[buf][aoff[m][1]];
            a[m] = cvt8(lo, hi);
        }
#pragma unroll
        for (int n = 0; n < 4; ++n)
            b[n] = *(const bf16x8*)&lds[buf][boff[n]];
#pragma unroll
        for (int m = 0; m < 4; ++m)
#pragma unroll
            for (int n = 0; n < 4; ++n)
                acc[m][n] = __builtin_amdgcn_mfma_f32_16x16x32_bf16(a[m], b[n], acc[m][n], 0, 0, 0);
    };

    stage(0, 0);
    __syncthreads();
#pragma unroll 1
    for (int kt = 0; kt < E; kt += 64) {
        stage(1, kt + 32);      // prefetch into buf1 (kt+32 <= 992 always)
        compute(0);
        __syncthreads();
        if (kt + 64 < E) stage(0, kt + 64);
        compute(1);
        __syncthreads();
    }

    // epilogue: C/D layout (16x16): col = lane&15, row = (lane>>4)*4 + q  [m89]
    const int ccol0 = bn0 + wn * 64 + r16;
    const int crow0 = am0 + wm * 64 + kg * 4;
    float bn_[4];
#pragma unroll
    for (int n = 0; n < 4; ++n) bn_[n] = ga.bias ? ga.bias[ccol0 + n * 16] : 0.f;
    CT* Cp = (CT*)ga.C;
#pragma unroll
    for (int m = 0; m < 4; ++m)
#pragma unroll
        for (int n = 0; n < 4; ++n)
#pragma unroll
            for (int qq = 0; qq < 4; ++qq) {
                size_t idx = (size_t)(crow0 + m * 16 + qq) * E + ccol0 + n * 16;
                cstore(Cp + idx, acc[m][n][qq] + bn_[n]);
            }
}

// ---------------- fused residual + LayerNorm (in-place on att/out) ----------------
struct LnArgs {
    const float* emb;
    const float* att;   // aliases out
    const float* scale;
    const float* g;
    const float* b;
    float* out;
};

__global__ __launch_bounds__(256) void ln_fused(LnArgs l0, LnArgs l1) {
    LnArgs la = blockIdx.z ? l1 : l0;
    const int row = blockIdx.x;
    const int t = threadIdx.x;
    const size_t off = (size_t)row * E + t * 4;
    f32x4 e = *(const f32x4*)(la.emb + off);
    f32x4 a = *(const f32x4*)(la.att + off);
    const float s = la.scale[0];
    f32x4 x = e + a * s;
    float sum = x[0] + x[1] + x[2] + x[3];
    float sq = x[0] * x[0] + x[1] * x[1] + x[2] * x[2] + x[3] * x[3];
#pragma unroll
    for (int o = 32; o; o >>= 1) { sum += __shfl_down(sum, o); sq += __shfl_down(sq, o); }
    __shared__ float rs[8];
    const int lane = t & 63, wid = t >> 6;
    if (lane == 0) { rs[wid] = sum; rs[wid + 4] = sq; }
    __syncthreads();
    sum = rs[0] + rs[1] + rs[2] + rs[3];
    sq = rs[4] + rs[5] + rs[6] + rs[7];
    const float mean = sum * (1.0f / E);
    const float var = sq * (1.0f / E) - mean * mean;
    const float rstd = rsqrtf(var + 1e-5f);
    f32x4 gv = *(const f32x4*)(la.g + t * 4);
    f32x4 bv = *(const f32x4*)(la.b + t * 4);
    f32x4 o = (x - mean) * rstd * gv + bv;
    *(f32x4*)(la.out + off) = o;
}

extern "C" void kernel_launch(void* const* d_in, const int* in_sizes, int n_in,
                              void* d_out, int out_size, void* d_ws, size_t ws_size,
                              hipStream_t stream) {
    const float* user_emb = (const float*)d_in[0];
    const float* item_emb = (const float*)d_in[1];
    const float* u2i_in_w = (const float*)d_in[2];
    const float* u2i_in_b = (const float*)d_in[3];
    const float* u2i_out_w = (const float*)d_in[4];
    const float* u2i_out_b = (const float*)d_in[5];
    const float* i2u_in_w = (const float*)d_in[6];
    const float* i2u_in_b = (const float*)d_in[7];
    const float* i2u_out_w = (const float*)d_in[8];
    const float* i2u_out_b = (const float*)d_in[9];
    const float* user_g = (const float*)d_in[10];
    const float* user_b = (const float*)d_in[11];
    const float* item_g = (const float*)d_in[12];
    const float* item_b = (const float*)d_in[13];
    const float* alpha = (const float*)d_in[14];
    const float* beta = (const float*)d_in[15];

    float* out = (float*)d_out;
    float* out_u = out;                    // user_evolved, also att_u scratch (f32)
    float* out_i = out + (size_t)NB * E;   // item_evolved, also att_i scratch

    // workspace layout (~8 MB)
    short* WvT1 = (short*)d_ws;
    short* WvT2 = WvT1 + (size_t)E * E;
    short* M1 = WvT2 + (size_t)E * E;
    short* M2 = M1 + (size_t)E * E;
    float* c1 = (float*)(M2 + (size_t)E * E);
    float* c2 = c1 + E;

    const dim3 b256(256);

    // 1) WvT = transpose(in_w[2E:3E]) in bf16
    wv_transpose<<<dim3(32, 32, 2), dim3(32, 8), 0, stream>>>(
        u2i_in_w + 2 * (size_t)E * E, WvT1, i2u_in_w + 2 * (size_t)E * E, WvT2);

    // 2) c = O @ bv + ob
    bias_fuse<<<dim3(E, 1, 2), b256, 0, stream>>>(
        u2i_out_w, u2i_in_b + 2 * E, u2i_out_b, c1,
        i2u_out_w, i2u_in_b + 2 * E, i2u_out_b, c2);

    // 3) M = O @ Wv   (bf16 output, [n][k] layout)  — 8x8x2 = 128 blocks
    gemm_bt<short><<<dim3(8 * 8 * 2), b256, 0, stream>>>(
        GemmArgs{u2i_out_w, WvT1, nullptr, (void*)M1},
        GemmArgs{i2u_out_w, WvT2, nullptr, (void*)M2}, 8);

    // 4) att = kv_emb @ M^T + c   (f32, straight into d_out halves) — 256x8x2 = 4096 blocks
    gemm_bt<float><<<dim3(256 * 8 * 2), b256, 0, stream>>>(
        GemmArgs{item_emb, M1, c1, (void*)out_u},
        GemmArgs{user_emb, M2, c2, (void*)out_i}, 256);

    // 5) out = LayerNorm(emb + scale*att) * g + b   (in-place on att)
    ln_fused<<<dim3(NB, 1, 2), b256, 0, stream>>>(
        LnArgs{user_emb, out_u, alpha, user_g, user_b, out_u},
        LnArgs{item_emb, out_i, beta, item_g, item_b, out_i});
}

// Round 3
// 396.614 us; speedup vs baseline: 2.3482x; 1.1130x over previous
//
#include <hip/hip_runtime.h>
#include <cstdint>
#include <cstddef>

#define E 1024
#define NB 32768
#define BM 128
#define BN 128

typedef __attribute__((ext_vector_type(4))) float f32x4;
typedef __attribute__((ext_vector_type(8))) short bf16x8;
typedef __attribute__((ext_vector_type(4))) short s16x4;

__device__ __forceinline__ short f2bfs(float x) {
    __bf16 h = (__bf16)x;
    return __builtin_bit_cast(short, h);
}
__device__ __forceinline__ float bf2f(short u) {
    union { unsigned u; float f; } v;
    v.u = ((unsigned)(unsigned short)u) << 16;
    return v.f;
}
__device__ __forceinline__ bf16x8 cvt8(f32x4 lo, f32x4 hi) {
    bf16x8 r;
#pragma unroll
    for (int j = 0; j < 4; ++j) { r[j] = f2bfs(lo[j]); r[j + 4] = f2bfs(hi[j]); }
    return r;
}

__device__ __forceinline__ void gload16(const void* g, void* l) {
    __builtin_amdgcn_global_load_lds(
        (__attribute__((address_space(1))) void*)g,
        (__attribute__((address_space(3))) void*)l, 16, 0, 0);
}

// ---------------- transpose f32 -> bf16 (Wv -> WvT) ----------------
__global__ __launch_bounds__(256) void wv_transpose(const float* W0, short* T0,
                                                    const float* W1, short* T1) {
    const float* W = blockIdx.z ? W1 : W0;
    short* T = blockIdx.z ? T1 : T0;
    __shared__ float tile[32][33];
    const int j0 = blockIdx.x * 32, i0 = blockIdx.y * 32;
    const int tx = threadIdx.x, ty = threadIdx.y; // (32,8)
#pragma unroll
    for (int r = 0; r < 4; ++r)
        tile[ty + 8 * r][tx] = W[(size_t)(i0 + ty + 8 * r) * E + j0 + tx];
    __syncthreads();
#pragma unroll
    for (int r = 0; r < 4; ++r)
        T[(size_t)(j0 + ty + 8 * r) * E + i0 + tx] = f2bfs(tile[tx][ty + 8 * r]);
}

// ---------------- c[n] = scale * (sum_i O[n][i]*bv[i] + ob[n]) ----------------
__global__ __launch_bounds__(256) void bias_fuse(const float* O0, const float* bv0, const float* ob0, const float* s0, float* c0,
                                                 const float* O1, const float* bv1, const float* ob1, const float* s1, float* c1) {
    const float* O  = blockIdx.z ? O1 : O0;
    const float* bv = blockIdx.z ? bv1 : bv0;
    const float* ob = blockIdx.z ? ob1 : ob0;
    const float* sc = blockIdx.z ? s1 : s0;
    float* c = blockIdx.z ? c1 : c0;
    const int n = blockIdx.x, t = threadIdx.x;
    float s = 0.f;
    for (int i = t; i < E; i += 256) s += O[(size_t)n * E + i] * bv[i];
#pragma unroll
    for (int o = 32; o; o >>= 1) s += __shfl_down(s, o);
    __shared__ float rs[4];
    if ((t & 63) == 0) rs[t >> 6] = s;
    __syncthreads();
    if (t == 0) c[n] = sc[0] * (rs[0] + rs[1] + rs[2] + rs[3] + ob[n]);
}

// ---------------- f32 -> bf16 convert into strided upper halves ----------------
__global__ __launch_bounds__(256) void conv_bf16(const float* s0, char* d0,
                                                 const float* s1, char* d1) {
    const float* s = blockIdx.z ? s1 : s0;
    char* d = blockIdx.z ? d1 : d0;
    const int stride = 4096 * 256;
    for (int i = blockIdx.x * 256 + threadIdx.x; i < NB * 128; i += stride) {
        int r = i >> 7, c = i & 127;
        const float* sp = s + (size_t)r * E + c * 8;
        f32x4 lo = *(const f32x4*)sp;
        f32x4 hi = *(const f32x4*)(sp + 4);
        *(bf16x8*)(d + (size_t)r * 4096 + c * 16) = cvt8(lo, hi);
    }
}

// ---------------- GEMM: C[m][n] = scale * sum_k A[m][k]*B[n][k] + bias[n] ----------------
// B: bf16 [1024][1024] ([n][k] linear). A: bf16 (ABF16) or f32, row stride arstride bytes.
// C: bf16, row stride crstride bytes. LDS double-buffered, XOR-swizzled (rule #21).
struct GemmArgs {
    const char* A;
    const short* B;
    const float* bias;   // may be null
    const float* scale;  // may be null (=1)
    char* C;
};

template <bool ABF16>
__global__ __launch_bounds__(256, ABF16 ? 4 : 3) void gemm_bt(GemmArgs g0, GemmArgs g1,
                                                              int mb, int arstride, int crstride) {
    // bijective XCD swizzle (nwg divisible by 8), n-block fastest within chunk
    const int nwg = gridDim.x;
    const int q = nwg >> 3;
    const int wgid = (blockIdx.x & 7) * q + (blockIdx.x >> 3);
    const int per = mb * 8;
    const int z = wgid / per;
    const int rem = wgid - z * per;
    const int bx = rem >> 3;   // m block
    const int by = rem & 7;    // n block
    GemmArgs ga = z ? g1 : g0;

    // per buffer: A at [0, ABYTES), B at [ABYTES, ABYTES+8192)
    constexpr int ABYTES = ABF16 ? 8192 : 16384;
    constexpr int BUFB = ABYTES + 8192;
    __shared__ __align__(16) char lds[2][BUFB];

    const int t = threadIdx.x;
    const int l = t & 63, w = t >> 6;
    const int am0 = bx * BM, bn0 = by * BN;

    // --- staging: per-thread global source addresses (inverse-swizzled) ---
    const char* gA[ABF16 ? 2 : 4];
    if constexpr (ABF16) {
#pragma unroll
        for (int i = 0; i < 2; ++i) {
            int c = i * 4 + w;                 // 8 chunks of 1KB
            int row = c * 16 + (l >> 2);
            int slot = (l & 3) ^ ((row >> 1) & 3);
            gA[i] = ga.A + (size_t)(am0 + row) * arstride + slot * 16;
        }
    } else {
#pragma unroll
        for (int i = 0; i < 4; ++i) {
            int c = i * 4 + w;                 // 16 chunks of 1KB
            int row = c * 8 + (l >> 3);
            int slot = (l & 7) ^ (row & 7);
            gA[i] = ga.A + (size_t)(am0 + row) * arstride + slot * 16;
        }
    }
    const short* gB[2];
#pragma unroll
    for (int i = 0; i < 2; ++i) {
        int c = i * 4 + w;                     // 8 chunks of 1KB
        int row = c * 16 + (l >> 2);
        int slot = (l & 3) ^ ((row >> 1) & 3);
        gB[i] = ga.B + (size_t)(bn0 + row) * E + slot * 8;
    }

    auto stage = [&](int buf, int kt) {
        if constexpr (ABF16) {
#pragma unroll
            for (int i = 0; i < 2; ++i)
                gload16(gA[i] + (size_t)kt * 2, &lds[buf][(i * 4 + w) * 1024]);
        } else {
#pragma unroll
            for (int i = 0; i < 4; ++i)
                gload16(gA[i] + (size_t)kt * 4, &lds[buf][(i * 4 + w) * 1024]);
        }
#pragma unroll
        for (int i = 0; i < 2; ++i)
            gload16(gB[i] + kt, &lds[buf][ABYTES + (i * 4 + w) * 1024]);
    };

    // --- read-side LDS byte offsets (swizzled) ---
    const int wm = w >> 1, wn = w & 1;
    const int r16 = l & 15, kg = l >> 4;
    int aoff[4][ABF16 ? 1 : 2], boff[4];
#pragma unroll
    for (int m = 0; m < 4; ++m) {
        int row = wm * 64 + m * 16 + r16;
        if constexpr (ABF16) {
            aoff[m][0] = row * 64 + (kg ^ ((row >> 1) & 3)) * 16;
        } else {
            aoff[m][0] = row * 128 + ((kg * 2) ^ (row & 7)) * 16;
            aoff[m][1] = row * 128 + ((kg * 2 + 1) ^ (row & 7)) * 16;
        }
    }
#pragma unroll
    for (int n = 0; n < 4; ++n) {
        int row = wn * 64 + n * 16 + r16;
        boff[n] = ABYTES + row * 64 + (kg ^ ((row >> 1) & 3)) * 16;
    }

    f32x4 acc[4][4] = {};

    auto compute = [&](int buf) {
        bf16x8 a[4], b[4];
#pragma unroll
        for (int m = 0; m < 4; ++m) {
            if constexpr (ABF16) {
                a[m] = *(const bf16x8*)&lds[buf][aoff[m][0]];
            } else {
                f32x4 lo = *(const f32x4*)&lds[buf][aoff[m][0]];
                f32x4 hi = *(const f32x4*)&lds[buf][aoff[m][1]];
                a[m] = cvt8(lo, hi);
            }
        }
#pragma unroll
        for (int n = 0; n < 4; ++n)
            b[n] = *(const bf16x8*)&lds[buf][boff[n]];
#pragma unroll
        for (int m = 0; m < 4; ++m)
#pragma unroll
            for (int n = 0; n < 4; ++n)
                acc[m][n] = __builtin_amdgcn_mfma_f32_16x16x32_bf16(a[m], b[n], acc[m][n], 0, 0, 0);
    };

    stage(0, 0);
    __syncthreads();
#pragma unroll 1
    for (int kt = 0; kt < E; kt += 64) {
        stage(1, kt + 32);
        compute(0);
        __syncthreads();
        if (kt + 64 < E) stage(0, kt + 64);
        compute(1);
        __syncthreads();
    }

    // epilogue: C/D layout (16x16): col = lane&15, row = (lane>>4)*4 + q  [m89]
    const int ccol0 = bn0 + wn * 64 + r16;
    const int crow0 = am0 + wm * 64 + kg * 4;
    const float sc = ga.scale ? ga.scale[0] : 1.f;
    float bn_[4];
#pragma unroll
    for (int n = 0; n < 4; ++n) bn_[n] = ga.bias ? ga.bias[ccol0 + n * 16] : 0.f;
#pragma unroll
    for (int m = 0; m < 4; ++m)
#pragma unroll
        for (int n = 0; n < 4; ++n)
#pragma unroll
            for (int qq = 0; qq < 4; ++qq) {
                int row = crow0 + m * 16 + qq;
                int col = ccol0 + n * 16;
                short* p = (short*)(ga.C + (size_t)row * crstride) + col;
                *p = f2bfs(acc[m][n][qq] * sc + bn_[n]);
            }
}

// ---------------- fused residual + LayerNorm ----------------
// att: bf16, row r at region + r*4096 bytes (lower 2KB); output f32 overwrites full slot.
struct LnArgs {
    const float* emb;  // B x E f32 (original input)
    char* region;      // att_bf16 in, f32 out (in-place per row slot)
    const float* g;
    const float* b;
};

__global__ __launch_bounds__(256) void ln_fused(LnArgs l0, LnArgs l1) {
    LnArgs la = blockIdx.z ? l1 : l0;
    const int row = blockIdx.x;
    const int t = threadIdx.x;
    char* base = la.region + (size_t)row * 4096;
    f32x4 e = *(const f32x4*)(la.emb + (size_t)row * E + t * 4);
    s16x4 av = *(const s16x4*)(base + t * 8);
    f32x4 x;
#pragma unroll
    for (int j = 0; j < 4; ++j) x[j] = e[j] + bf2f(av[j]);
    float sum = x[0] + x[1] + x[2] + x[3];
    float sq = x[0] * x[0] + x[1] * x[1] + x[2] * x[2] + x[3] * x[3];
#pragma unroll
    for (int o = 32; o; o >>= 1) { sum += __shfl_down(sum, o); sq += __shfl_down(sq, o); }
    __shared__ float rs[8];
    const int lane = t & 63, wid = t >> 6;
    if (lane == 0) { rs[wid] = sum; rs[wid + 4] = sq; }
    __syncthreads();   // also orders: all att reads complete before any write below
    sum = rs[0] + rs[1] + rs[2] + rs[3];
    sq = rs[4] + rs[5] + rs[6] + rs[7];
    const float mean = sum * (1.0f / E);
    const float var = sq * (1.0f / E) - mean * mean;
    const float rstd = rsqrtf(var + 1e-5f);
    f32x4 gv = *(const f32x4*)(la.g + t * 4);
    f32x4 bv = *(const f32x4*)(la.b + t * 4);
    f32x4 o = (x - mean) * rstd * gv + bv;
    *(f32x4*)(base + t * 16) = o;
}

extern "C" void kernel_launch(void* const* d_in, const int* in_sizes, int n_in,
                              void* d_out, int out_size, void* d_ws, size_t ws_size,
                              hipStream_t stream) {
    const float* user_emb = (const float*)d_in[0];
    const float* item_emb = (const float*)d_in[1];
    const float* u2i_in_w = (const float*)d_in[2];
    const float* u2i_in_b = (const float*)d_in[3];
    const float* u2i_out_w = (const float*)d_in[4];
    const float* u2i_out_b = (const float*)d_in[5];
    const float* i2u_in_w = (const float*)d_in[6];
    const float* i2u_in_b = (const float*)d_in[7];
    const float* i2u_out_w = (const float*)d_in[8];
    const float* i2u_out_b = (const float*)d_in[9];
    const float* user_g = (const float*)d_in[10];
    const float* user_b = (const float*)d_in[11];
    const float* item_g = (const float*)d_in[12];
    const float* item_b = (const float*)d_in[13];
    const float* alpha = (const float*)d_in[14];
    const float* beta = (const float*)d_in[15];

    // output regions: per-table 32768 slots x 4096B.
    // slot r = [att_bf16 row r (2KB) | other-table emb_bf16 row r (2KB)] until LN overwrites with f32.
    char* OU = (char*)d_out;                       // user side: att_u | item_emb_bf16
    char* OI = OU + (size_t)NB * 4096;             // item side: att_i | user_emb_bf16

    // workspace (~8.4 MB)
    short* WvT1 = (short*)d_ws;
    short* WvT2 = WvT1 + (size_t)E * E;
    short* M1 = WvT2 + (size_t)E * E;
    short* M2 = M1 + (size_t)E * E;
    float* c1 = (float*)(M2 + (size_t)E * E);
    float* c2 = c1 + E;

    const dim3 b256(256);

    // 1) WvT = transpose(in_w[2E:3E]) in bf16
    wv_transpose<<<dim3(32, 32, 2), dim3(32, 8), 0, stream>>>(
        u2i_in_w + 2 * (size_t)E * E, WvT1, i2u_in_w + 2 * (size_t)E * E, WvT2);

    // 2) c = scale * (O @ bv + ob)   (alpha/beta folded in)
    bias_fuse<<<dim3(E, 1, 2), b256, 0, stream>>>(
        u2i_out_w, u2i_in_b + 2 * E, u2i_out_b, alpha, c1,
        i2u_out_w, i2u_in_b + 2 * E, i2u_out_b, beta, c2);

    // 3) emb -> bf16 into upper halves of output slots
    conv_bf16<<<dim3(4096, 1, 2), b256, 0, stream>>>(
        item_emb, OU + 2048, user_emb, OI + 2048);

    // 4) M = scale * (O @ Wv)   bf16 [n][k], f32-A path, 128 blocks
    gemm_bt<false><<<dim3(8 * 8 * 2), b256, 0, stream>>>(
        GemmArgs{(const char*)u2i_out_w, WvT1, nullptr, alpha, (char*)M1},
        GemmArgs{(const char*)i2u_out_w, WvT2, nullptr, beta, (char*)M2},
        8, 4096, 2048);

    // 5) att = emb_bf16 @ M^T + c   (bf16 into lower halves), 4096 blocks
    gemm_bt<true><<<dim3(256 * 8 * 2), b256, 0, stream>>>(
        GemmArgs{OU + 2048, M1, c1, nullptr, OU},
        GemmArgs{OI + 2048, M2, c2, nullptr, OI},
        256, 4096, 4096);

    // 6) out = LayerNorm(emb + att) * g + b   (in-place: bf16 att slot -> f32 row)
    ln_fused<<<dim3(NB, 1, 2), b256, 0, stream>>>(
        LnArgs{user_emb, OU, user_g, user_b},
        LnArgs{item_emb, OI, item_g, item_b});
}

// Round 4
// 332.298 us; speedup vs baseline: 2.8027x; 1.1935x over previous
//
#include <hip/hip_runtime.h>
#include <cstdint>
#include <cstddef>

#define E 1024
#define NB 32768
#define BM 128
#define BN 128

typedef __attribute__((ext_vector_type(4))) float f32x4;
typedef __attribute__((ext_vector_type(8))) short bf16x8;
typedef __attribute__((ext_vector_type(4))) short s16x4;

__device__ __forceinline__ short f2bfs(float x) {
    __bf16 h = (__bf16)x;
    return __builtin_bit_cast(short, h);
}
__device__ __forceinline__ float bf2f(short u) {
    union { unsigned u; float f; } v;
    v.u = ((unsigned)(unsigned short)u) << 16;
    return v.f;
}
__device__ __forceinline__ bf16x8 cvt8(f32x4 lo, f32x4 hi) {
    bf16x8 r;
#pragma unroll
    for (int j = 0; j < 4; ++j) { r[j] = f2bfs(lo[j]); r[j + 4] = f2bfs(hi[j]); }
    return r;
}

__device__ __forceinline__ void gload16(const void* g, void* l) {
    __builtin_amdgcn_global_load_lds(
        (__attribute__((address_space(1))) void*)g,
        (__attribute__((address_space(3))) void*)l, 16, 0, 0);
}

// ---------------- transpose f32 -> bf16 (Wv -> WvT) ----------------
__global__ __launch_bounds__(256) void wv_transpose(const float* W0, short* T0,
                                                    const float* W1, short* T1) {
    const float* W = blockIdx.z ? W1 : W0;
    short* T = blockIdx.z ? T1 : T0;
    __shared__ float tile[32][33];
    const int j0 = blockIdx.x * 32, i0 = blockIdx.y * 32;
    const int tx = threadIdx.x, ty = threadIdx.y; // (32,8)
#pragma unroll
    for (int r = 0; r < 4; ++r)
        tile[ty + 8 * r][tx] = W[(size_t)(i0 + ty + 8 * r) * E + j0 + tx];
    __syncthreads();
#pragma unroll
    for (int r = 0; r < 4; ++r)
        T[(size_t)(j0 + ty + 8 * r) * E + i0 + tx] = f2bfs(tile[tx][ty + 8 * r]);
}

// ---------------- c[n] = scale * (sum_i O[n][i]*bv[i] + ob[n]) ----------------
__global__ __launch_bounds__(256) void bias_fuse(const float* O0, const float* bv0, const float* ob0, const float* s0, float* c0,
                                                 const float* O1, const float* bv1, const float* ob1, const float* s1, float* c1) {
    const float* O  = blockIdx.z ? O1 : O0;
    const float* bv = blockIdx.z ? bv1 : bv0;
    const float* ob = blockIdx.z ? ob1 : ob0;
    const float* sc = blockIdx.z ? s1 : s0;
    float* c = blockIdx.z ? c1 : c0;
    const int n = blockIdx.x, t = threadIdx.x;
    float s = 0.f;
    for (int i = t; i < E; i += 256) s += O[(size_t)n * E + i] * bv[i];
#pragma unroll
    for (int o = 32; o; o >>= 1) s += __shfl_down(s, o);
    __shared__ float rs[4];
    if ((t & 63) == 0) rs[t >> 6] = s;
    __syncthreads();
    if (t == 0) c[n] = sc[0] * (rs[0] + rs[1] + rs[2] + rs[3] + ob[n]);
}

// ---------------- small GEMM (round-3 proven): C[m][n] = scale * sum_k A[m][k]*B[n][k] ----------------
struct GemmArgs {
    const char* A;
    const short* B;
    const float* bias;
    const float* scale;
    char* C;
};

template <bool ABF16>
__global__ __launch_bounds__(256, ABF16 ? 4 : 3) void gemm_bt(GemmArgs g0, GemmArgs g1,
                                                              int mb, int arstride, int crstride) {
    const int nwg = gridDim.x;
    const int q = nwg >> 3;
    const int wgid = (blockIdx.x & 7) * q + (blockIdx.x >> 3);
    const int per = mb * 8;
    const int z = wgid / per;
    const int rem = wgid - z * per;
    const int bx = rem >> 3;
    const int by = rem & 7;
    GemmArgs ga = z ? g1 : g0;

    constexpr int ABYTES = ABF16 ? 8192 : 16384;
    constexpr int BUFB = ABYTES + 8192;
    __shared__ __align__(16) char lds[2][BUFB];

    const int t = threadIdx.x;
    const int l = t & 63, w = t >> 6;
    const int am0 = bx * BM, bn0 = by * BN;

    const char* gA[ABF16 ? 2 : 4];
    if constexpr (ABF16) {
#pragma unroll
        for (int i = 0; i < 2; ++i) {
            int c = i * 4 + w;
            int row = c * 16 + (l >> 2);
            int slot = (l & 3) ^ ((row >> 1) & 3);
            gA[i] = ga.A + (size_t)(am0 + row) * arstride + slot * 16;
        }
    } else {
#pragma unroll
        for (int i = 0; i < 4; ++i) {
            int c = i * 4 + w;
            int row = c * 8 + (l >> 3);
            int slot = (l & 7) ^ (row & 7);
            gA[i] = ga.A + (size_t)(am0 + row) * arstride + slot * 16;
        }
    }
    const short* gB[2];
#pragma unroll
    for (int i = 0; i < 2; ++i) {
        int c = i * 4 + w;
        int row = c * 16 + (l >> 2);
        int slot = (l & 3) ^ ((row >> 1) & 3);
        gB[i] = ga.B + (size_t)(bn0 + row) * E + slot * 8;
    }

    auto stage = [&](int buf, int kt) {
        if constexpr (ABF16) {
#pragma unroll
            for (int i = 0; i < 2; ++i)
                gload16(gA[i] + (size_t)kt * 2, &lds[buf][(i * 4 + w) * 1024]);
        } else {
#pragma unroll
            for (int i = 0; i < 4; ++i)
                gload16(gA[i] + (size_t)kt * 4, &lds[buf][(i * 4 + w) * 1024]);
        }
#pragma unroll
        for (int i = 0; i < 2; ++i)
            gload16(gB[i] + kt, &lds[buf][ABYTES + (i * 4 + w) * 1024]);
    };

    const int wm = w >> 1, wn = w & 1;
    const int r16 = l & 15, kg = l >> 4;
    int aoff[4][ABF16 ? 1 : 2], boff[4];
#pragma unroll
    for (int m = 0; m < 4; ++m) {
        int row = wm * 64 + m * 16 + r16;
        if constexpr (ABF16) {
            aoff[m][0] = row * 64 + (kg ^ ((row >> 1) & 3)) * 16;
        } else {
            aoff[m][0] = row * 128 + ((kg * 2) ^ (row & 7)) * 16;
            aoff[m][1] = row * 128 + ((kg * 2 + 1) ^ (row & 7)) * 16;
        }
    }
#pragma unroll
    for (int n = 0; n < 4; ++n) {
        int row = wn * 64 + n * 16 + r16;
        boff[n] = ABYTES + row * 64 + (kg ^ ((row >> 1) & 3)) * 16;
    }

    f32x4 acc[4][4] = {};

    auto compute = [&](int buf) {
        bf16x8 a[4], b[4];
#pragma unroll
        for (int m = 0; m < 4; ++m) {
            if constexpr (ABF16) {
                a[m] = *(const bf16x8*)&lds[buf][aoff[m][0]];
            } else {
                f32x4 lo = *(const f32x4*)&lds[buf][aoff[m][0]];
                f32x4 hi = *(const f32x4*)&lds[buf][aoff[m][1]];
                a[m] = cvt8(lo, hi);
            }
        }
#pragma unroll
        for (int n = 0; n < 4; ++n)
            b[n] = *(const bf16x8*)&lds[buf][boff[n]];
#pragma unroll
        for (int m = 0; m < 4; ++m)
#pragma unroll
            for (int n = 0; n < 4; ++n)
                acc[m][n] = __builtin_amdgcn_mfma_f32_16x16x32_bf16(a[m], b[n], acc[m][n], 0, 0, 0);
    };

    stage(0, 0);
    __syncthreads();
#pragma unroll 1
    for (int kt = 0; kt < E; kt += 64) {
        stage(1, kt + 32);
        compute(0);
        __syncthreads();
        if (kt + 64 < E) stage(0, kt + 64);
        compute(1);
        __syncthreads();
    }

    const int ccol0 = bn0 + wn * 64 + r16;
    const int crow0 = am0 + wm * 64 + kg * 4;
    const float sc = ga.scale ? ga.scale[0] : 1.f;
    float bn_[4];
#pragma unroll
    for (int n = 0; n < 4; ++n) bn_[n] = ga.bias ? ga.bias[ccol0 + n * 16] : 0.f;
#pragma unroll
    for (int m = 0; m < 4; ++m)
#pragma unroll
        for (int n = 0; n < 4; ++n)
#pragma unroll
            for (int qq = 0; qq < 4; ++qq) {
                int row = crow0 + m * 16 + qq;
                int col = ccol0 + n * 16;
                short* p = (short*)(ga.C + (size_t)row * crstride) + col;
                *p = f2bfs(acc[m][n][qq] * sc + bn_[n]);
            }
}

// ============ fused: out = LN(q_emb + (kv_emb @ M^T + c)) * g + b ============
// Tile: 64 rows x full 1024 cols, 8 waves (wave = 64x128), BK=32 double-buffered.
// A (kv f32) reg-staged -> cvt -> ds_write (swizzled). B (M bf16, L2-hot) via gload_lds.
struct FArgs {
    const float* kv;   // [32768][1024] f32  (GEMM A)
    const short* M;    // [1024][1024] bf16  [n][k], alpha folded
    const float* c;    // [1024] f32, alpha folded
    const float* q;    // [32768][1024] f32  (residual emb)
    const float* g;
    const float* b;
    float* out;        // [32768][1024] f32
};

#define ABUF(buf) ((buf) * 4096)
#define BBUF(buf) (8192 + (buf) * 65536)

__global__ __launch_bounds__(512, 2) void fused_gemm_ln(FArgs f0, FArgs f1) {
    // 1024 blocks; XCD-chunked: XCDs 0-3 -> table 0, 4-7 -> table 1; M stays L2-hot.
    const int bid = blockIdx.x;
    const int wgid = (bid & 7) * 128 + (bid >> 3);
    const int z = wgid >> 9;
    const int mb = wgid & 511;
    const FArgs fa = z ? f1 : f0;
    const int r0 = mb * 64;

    __shared__ __align__(16) char lds[139264]; // A: 2x4KB @0, B: 2x64KB @8192

    const int t = threadIdx.x;
    const int l = t & 63, w = t >> 6;
    const int r16 = l & 15, kg = l >> 4;

    // B staging: chunk c covers global idx g=c*512+t; row=g>>2, slot=g&3 (16B units)
    int bsrc[8];
#pragma unroll
    for (int c = 0; c < 8; ++c) {
        int gi = c * 512 + t;
        int row = gi >> 2, slot = gi & 3;
        int ss = slot ^ ((row >> 1) & 3);   // inverse swizzle on source
        bsrc[c] = row * 2048 + ss * 16;
    }
    // A staging: thread -> (row, 16B-f32-chunk)
    const int ar = t >> 3, ach = t & 7;
    const float* asrc = fa.kv + (size_t)(r0 + ar) * E + ach * 4;
    const int awoff = ar * 64 + (((ach >> 1) ^ ((ar >> 1) & 3)) * 16) + (ach & 1) * 8;

    // read-side swizzled offsets
    int aoff[4], boff[8];
#pragma unroll
    for (int m = 0; m < 4; ++m) {
        int row = m * 16 + r16;
        aoff[m] = row * 64 + (kg ^ ((row >> 1) & 3)) * 16;
    }
#pragma unroll
    for (int n = 0; n < 8; ++n) {
        int row = w * 128 + n * 16 + r16;
        boff[n] = row * 64 + (kg ^ ((row >> 1) & 3)) * 16;
    }

    f32x4 acc[4][8] = {};

    auto stageB = [&](int buf, int kt) {
#pragma unroll
        for (int c = 0; c < 8; ++c)
            gload16((const char*)fa.M + bsrc[c] + kt * 2,
                    &lds[BBUF(buf) + c * 8192 + w * 1024]);
    };
    auto commitA = [&](int buf, f32x4 av) {
        s16x4 v;
#pragma unroll
        for (int j = 0; j < 4; ++j) v[j] = f2bfs(av[j]);
        *(s16x4*)&lds[ABUF(buf) + awoff] = v;
    };
    auto compute = [&](int buf) {
        bf16x8 a[4], b[8];
#pragma unroll
        for (int m = 0; m < 4; ++m)
            a[m] = *(const bf16x8*)&lds[ABUF(buf) + aoff[m]];
#pragma unroll
        for (int n = 0; n < 8; ++n)
            b[n] = *(const bf16x8*)&lds[BBUF(buf) + boff[n]];
#pragma unroll
        for (int m = 0; m < 4; ++m)
#pragma unroll
            for (int n = 0; n < 8; ++n)
                acc[m][n] = __builtin_amdgcn_mfma_f32_16x16x32_bf16(a[m], b[n], acc[m][n], 0, 0, 0);
    };

    {
        f32x4 a0 = *(const f32x4*)(asrc + 0);
        stageB(0, 0);
        commitA(0, a0);
    }
    __syncthreads();
#pragma unroll 1
    for (int kt = 0; kt < E; kt += 64) {
        const bool has = (kt + 64) < E;
        f32x4 a1 = *(const f32x4*)(asrc + kt + 32);
        f32x4 a2;
        if (has) a2 = *(const f32x4*)(asrc + kt + 64);
        stageB(1, kt + 32);
        compute(0);
        commitA(1, a1);
        __syncthreads();
        if (has) stageB(0, kt + 64);
        compute(1);
        if (has) commitA(0, a2);
        __syncthreads();
    }

    // ---- epilogue: residual + LayerNorm ----
    float* S  = (float*)lds;            // [64][8] row sums
    float* Q  = (float*)(lds + 2048);   // [64][8] row sumsq
    float* CB = (float*)(lds + 4096);   // [64][2] mean,rstd

    const int colbase = w * 128 + r16;
    float cf[8];
#pragma unroll
    for (int n = 0; n < 8; ++n) cf[n] = fa.c[colbase + n * 16];

    float sum_[4][4] = {}, sq_[4][4] = {};
#pragma unroll
    for (int m = 0; m < 4; ++m) {
#pragma unroll
        for (int n = 0; n < 8; ++n) {
#pragma unroll
            for (int qq = 0; qq < 4; ++qq) {
                int lrow = m * 16 + kg * 4 + qq;
                float x = acc[m][n][qq] + cf[n] + fa.q[(size_t)(r0 + lrow) * E + colbase + n * 16];
                acc[m][n][qq] = x;
                sum_[m][qq] += x;
                sq_[m][qq] += x * x;
            }
        }
    }
    // butterfly across the 16-lane group sharing these rows
#pragma unroll
    for (int m = 0; m < 4; ++m)
#pragma unroll
        for (int qq = 0; qq < 4; ++qq)
#pragma unroll
            for (int o = 1; o < 16; o <<= 1) {
                sum_[m][qq] += __shfl_xor(sum_[m][qq], o);
                sq_[m][qq] += __shfl_xor(sq_[m][qq], o);
            }
    // writer lane per (m,qq): r16 == m*4+qq (bijective over 16 lanes)
#pragma unroll
    for (int m = 0; m < 4; ++m)
#pragma unroll
        for (int qq = 0; qq < 4; ++qq)
            if (r16 == m * 4 + qq) {
                int lrow = m * 16 + kg * 4 + qq;
                S[lrow * 8 + w] = sum_[m][qq];
                Q[lrow * 8 + w] = sq_[m][qq];
            }
    __syncthreads();
    if (t < 64) {
        f32x4 s0 = *(const f32x4*)(S + t * 8);
        f32x4 s1 = *(const f32x4*)(S + t * 8 + 4);
        f32x4 q0 = *(const f32x4*)(Q + t * 8);
        f32x4 q1 = *(const f32x4*)(Q + t * 8 + 4);
        float ss = s0[0] + s0[1] + s0[2] + s0[3] + s1[0] + s1[1] + s1[2] + s1[3];
        float qs = q0[0] + q0[1] + q0[2] + q0[3] + q1[0] + q1[1] + q1[2] + q1[3];
        float mean = ss * (1.0f / E);
        float var = qs * (1.0f / E) - mean * mean;
        CB[t * 2] = mean;
        CB[t * 2 + 1] = rsqrtf(var + 1e-5f);
    }
    __syncthreads();

    float gf[8], bf_[8];
#pragma unroll
    for (int n = 0; n < 8; ++n) {
        gf[n] = fa.g[colbase + n * 16];
        bf_[n] = fa.b[colbase + n * 16];
    }
#pragma unroll
    for (int m = 0; m < 4; ++m)
#pragma unroll
        for (int qq = 0; qq < 4; ++qq) {
            int lrow = m * 16 + kg * 4 + qq;
            float mean = CB[lrow * 2], rstd = CB[lrow * 2 + 1];
            float* op = fa.out + (size_t)(r0 + lrow) * E + colbase;
#pragma unroll
            for (int n = 0; n < 8; ++n)
                op[n * 16] = (acc[m][n][qq] - mean) * rstd * gf[n] + bf_[n];
        }
}

extern "C" void kernel_launch(void* const* d_in, const int* in_sizes, int n_in,
                              void* d_out, int out_size, void* d_ws, size_t ws_size,
                              hipStream_t stream) {
    const float* user_emb = (const float*)d_in[0];
    const float* item_emb = (const float*)d_in[1];
    const float* u2i_in_w = (const float*)d_in[2];
    const float* u2i_in_b = (const float*)d_in[3];
    const float* u2i_out_w = (const float*)d_in[4];
    const float* u2i_out_b = (const float*)d_in[5];
    const float* i2u_in_w = (const float*)d_in[6];
    const float* i2u_in_b = (const float*)d_in[7];
    const float* i2u_out_w = (const float*)d_in[8];
    const float* i2u_out_b = (const float*)d_in[9];
    const float* user_g = (const float*)d_in[10];
    const float* user_b = (const float*)d_in[11];
    const float* item_g = (const float*)d_in[12];
    const float* item_b = (const float*)d_in[13];
    const float* alpha = (const float*)d_in[14];
    const float* beta = (const float*)d_in[15];

    float* out_u = (float*)d_out;
    float* out_i = out_u + (size_t)NB * E;

    // workspace (~8.4 MB)
    short* WvT1 = (short*)d_ws;
    short* WvT2 = WvT1 + (size_t)E * E;
    short* M1 = WvT2 + (size_t)E * E;
    short* M2 = M1 + (size_t)E * E;
    float* c1 = (float*)(M2 + (size_t)E * E);
    float* c2 = c1 + E;

    const dim3 b256(256);

    // 1) WvT = transpose(in_w[2E:3E]) in bf16
    wv_transpose<<<dim3(32, 32, 2), dim3(32, 8), 0, stream>>>(
        u2i_in_w + 2 * (size_t)E * E, WvT1, i2u_in_w + 2 * (size_t)E * E, WvT2);

    // 2) c = scale * (O @ bv + ob)
    bias_fuse<<<dim3(E, 1, 2), b256, 0, stream>>>(
        u2i_out_w, u2i_in_b + 2 * E, u2i_out_b, alpha, c1,
        i2u_out_w, i2u_in_b + 2 * E, i2u_out_b, beta, c2);

    // 3) M = scale * (O @ Wv)   bf16 [n][k]
    gemm_bt<false><<<dim3(8 * 8 * 2), b256, 0, stream>>>(
        GemmArgs{(const char*)u2i_out_w, WvT1, nullptr, alpha, (char*)M1},
        GemmArgs{(const char*)i2u_out_w, WvT2, nullptr, beta, (char*)M2},
        8, 4096, 2048);

    // 4) fused GEMM + residual + LayerNorm (1024 blocks x 512 threads)
    fused_gemm_ln<<<dim3(1024), dim3(512), 0, stream>>>(
        FArgs{item_emb, M1, c1, user_emb, user_g, user_b, out_u},
        FArgs{user_emb, M2, c2, item_emb, item_g, item_b, out_i});
}